// Round 5
// baseline (148.246 us; speedup 1.0000x reference)
//
#include <hip/hip_runtime.h>

namespace {

constexpr int    TT     = 2048;
constexpr int    BB     = 128;
constexpr int    CHUNK  = 16;                 // 16-lane shfl scan width
constexpr int    RLEN   = 1024;               // timesteps per round (== block size)
constexpr int    NCH    = RLEN / CHUNK;       // 64 chunks per round
constexpr int    ROUNDS = TT / RLEN;          // 2
constexpr float  DT     = 0.02f;
constexpr size_t HALF   = (size_t)TT * BB * 16;  // floats per (real|imag) half of d_out
constexpr int    PITCH  = 33;                 // LDS row pitch (32 floats + 1 pad)

// C = A @ B, complex 4x4, row-major flat [16]
__device__ __forceinline__ void cmm(const float* __restrict__ ar, const float* __restrict__ ai,
                                    const float* __restrict__ br, const float* __restrict__ bi,
                                    float* __restrict__ cr, float* __restrict__ ci) {
#pragma unroll
    for (int i = 0; i < 4; ++i) {
#pragma unroll
        for (int j = 0; j < 4; ++j) {
            float sr = 0.f, si = 0.f;
#pragma unroll
            for (int k = 0; k < 4; ++k) {
                const float xr = ar[i * 4 + k], xi = ai[i * 4 + k];
                const float yr = br[k * 4 + j], yi = bi[k * 4 + j];
                sr = fmaf(xr, yr, sr);
                sr = fmaf(-xi, yi, sr);
                si = fmaf(xr, yi, si);
                si = fmaf(xi, yr, si);
            }
            cr[i * 4 + j] = sr;
            ci[i * 4 + j] = si;
        }
    }
}

} // namespace

// ---------------------------------------------------------------------------
// One block per batch (128 blocks x 1024 threads), 2 rounds of 1024 steps.
// Per round: expm (deg-4 PS) + 16-lane KS chunk prefix (regs) -> chunk totals
// to LDS -> wave 0 KS-scans the 64 totals (seeded with running base) ->
// carries in LDS -> out = P @ carry written straight to d_out.
// No grid sync, no cooperative launch, no L round-trip through HBM.
// launch_bounds(1024,4): 16-wave block needs 4 waves/SIMD -> VGPR <= 128.
// ---------------------------------------------------------------------------
__global__ __launch_bounds__(1024, 4) void kFused(const float* __restrict__ hr,
                                                  const float* __restrict__ hi,
                                                  const float* __restrict__ sr0,
                                                  const float* __restrict__ si0,
                                                  float* __restrict__ out) {
    __shared__ float sTot[NCH * PITCH];   // chunk totals   [ct][0..15 re | 16..31 im]
    __shared__ float sCar[NCH * PITCH];   // chunk carries  (same layout)
    __shared__ float sBase[32];           // running base matrix (re|im)

    const int tid   = threadIdx.x;
    const int b     = blockIdx.x;
    const int chunk = tid >> 4;
    const int sub   = tid & 15;
    const int lane  = tid & 63;

    if (tid < 16) {
        sBase[tid]      = sr0[b * 16 + tid];
        sBase[16 + tid] = si0[b * 16 + tid];
    }

    for (int r = 0; r < ROUNDS; ++r) {
        const int t = r * RLEN + tid;

        // ---- load A = -i*DT*H  (a_r = DT*hi, a_i = -DT*hr), coalesced
        float a_r[16], a_i[16];
        {
            const float4* p4r = reinterpret_cast<const float4*>(hr) + ((size_t)b * TT + t) * 4;
            const float4* p4i = reinterpret_cast<const float4*>(hi) + ((size_t)b * TT + t) * 4;
#pragma unroll
            for (int v = 0; v < 4; ++v) {
                const float4 rr = p4r[v];
                const float4 im = p4i[v];
                a_r[v * 4 + 0] = DT * im.x;  a_i[v * 4 + 0] = -DT * rr.x;
                a_r[v * 4 + 1] = DT * im.y;  a_i[v * 4 + 1] = -DT * rr.y;
                a_r[v * 4 + 2] = DT * im.z;  a_i[v * 4 + 2] = -DT * rr.z;
                a_r[v * 4 + 3] = DT * im.w;  a_i[v * 4 + 3] = -DT * rr.w;
            }
        }

        // ---- expm deg-4 PS:  E = I + A + A2 @ (I/2 + A/6 + A2/24)
        float er[16], ei[16];
        {
            float a2r[16], a2i[16];
            cmm(a_r, a_i, a_r, a_i, a2r, a2i);
            float tr[16], ti[16];
#pragma unroll
            for (int e = 0; e < 16; ++e) {
                const float d = (e % 5 == 0) ? 1.0f : 0.0f;
                tr[e] = fmaf(a_r[e], 1.f / 6.f, d * 0.5f);
                tr[e] = fmaf(a2r[e], 1.f / 24.f, tr[e]);
                ti[e] = a_i[e] * (1.f / 6.f);
                ti[e] = fmaf(a2i[e], 1.f / 24.f, ti[e]);
            }
            cmm(a2r, a2i, tr, ti, er, ei);
#pragma unroll
            for (int e = 0; e < 16; ++e) {
                const float d = (e % 5 == 0) ? 1.0f : 0.0f;
                er[e] = er[e] + d + a_r[e];
                ei[e] = ei[e] + a_i[e];
            }
        }

        // ---- 16-lane Kogge-Stone chunk prefix:  P = U[sub] @ ... @ U[0]
#pragma unroll
        for (int d = 1; d < CHUNK; d <<= 1) {
            int src = lane - d;
            if (src < 0) src = 0;           // clamped junk, discarded by select
            float qr[16], qi[16];
#pragma unroll
            for (int e = 0; e < 16; ++e) {
                qr[e] = __shfl(er[e], src, 64);
                qi[e] = __shfl(ei[e], src, 64);
            }
            float nr[16], ni[16];
            cmm(er, ei, qr, qi, nr, ni);
            const bool pred = (sub >= d);
#pragma unroll
            for (int e = 0; e < 16; ++e) {
                er[e] = pred ? nr[e] : er[e];
                ei[e] = pred ? ni[e] : ei[e];
            }
        }

        // ---- chunk totals to LDS
        if (sub == CHUNK - 1) {
#pragma unroll
            for (int e = 0; e < 16; ++e) {
                sTot[chunk * PITCH + e]      = er[e];
                sTot[chunk * PITCH + 16 + e] = ei[e];
            }
        }
        __syncthreads();

        // ---- wave 0: KS scan of [base, T0..T62] -> carry[ct]; lane63 makes new base
        if (tid < NCH) {
            float mr[16], mi[16];
            if (tid == 0) {
#pragma unroll
                for (int e = 0; e < 16; ++e) { mr[e] = sBase[e]; mi[e] = sBase[16 + e]; }
            } else {
#pragma unroll
                for (int e = 0; e < 16; ++e) {
                    mr[e] = sTot[(tid - 1) * PITCH + e];
                    mi[e] = sTot[(tid - 1) * PITCH + 16 + e];
                }
            }
#pragma unroll
            for (int d = 1; d < NCH; d <<= 1) {
                int src = lane - d;
                if (src < 0) src = 0;
                float qr[16], qi[16];
#pragma unroll
                for (int e = 0; e < 16; ++e) {
                    qr[e] = __shfl(mr[e], src, 64);
                    qi[e] = __shfl(mi[e], src, 64);
                }
                float nr[16], ni[16];
                cmm(mr, mi, qr, qi, nr, ni);
                const bool pred = (lane >= d);
#pragma unroll
                for (int e = 0; e < 16; ++e) {
                    mr[e] = pred ? nr[e] : mr[e];
                    mi[e] = pred ? ni[e] : mi[e];
                }
            }
#pragma unroll
            for (int e = 0; e < 16; ++e) {
                sCar[tid * PITCH + e]      = mr[e];
                sCar[tid * PITCH + 16 + e] = mi[e];
            }
            if (tid == NCH - 1) {
                // new base = T[63] @ S[63]  (full-round total applied to base)
                float t3r[16], t3i[16], nbr[16], nbi[16];
#pragma unroll
                for (int e = 0; e < 16; ++e) {
                    t3r[e] = sTot[(NCH - 1) * PITCH + e];
                    t3i[e] = sTot[(NCH - 1) * PITCH + 16 + e];
                }
                cmm(t3r, t3i, mr, mi, nbr, nbi);
#pragma unroll
                for (int e = 0; e < 16; ++e) {
                    sBase[e]      = nbr[e];
                    sBase[16 + e] = nbi[e];
                }
            }
        }
        __syncthreads();

        // ---- finalize: out[t][b] = P @ carry[chunk]
        float c_r[16], c_i[16];
#pragma unroll
        for (int e = 0; e < 16; ++e) {
            c_r[e] = sCar[chunk * PITCH + e];
            c_i[e] = sCar[chunk * PITCH + 16 + e];
        }
        float o_r[16], o_i[16];
        cmm(er, ei, c_r, c_i, o_r, o_i);

        const size_t oi = ((size_t)t * BB + b) * 16;
        float4* orp = reinterpret_cast<float4*>(out + oi);
        float4* oip = reinterpret_cast<float4*>(out + HALF + oi);
#pragma unroll
        for (int v = 0; v < 4; ++v) {
            orp[v] = make_float4(o_r[v * 4 + 0], o_r[v * 4 + 1], o_r[v * 4 + 2], o_r[v * 4 + 3]);
            oip[v] = make_float4(o_i[v * 4 + 0], o_i[v * 4 + 1], o_i[v * 4 + 2], o_i[v * 4 + 3]);
        }
    }
}

extern "C" void kernel_launch(void* const* d_in, const int* in_sizes, int n_in,
                              void* d_out, int out_size, void* d_ws, size_t ws_size,
                              hipStream_t stream) {
    const float* hr = (const float*)d_in[0];
    const float* hi = (const float*)d_in[1];
    const float* sr = (const float*)d_in[2];
    const float* si = (const float*)d_in[3];
    float* out = (float*)d_out;

    kFused<<<BB, RLEN, 0, stream>>>(hr, hi, sr, si, out);
}

// Round 6
// 121.560 us; speedup vs baseline: 1.2195x; 1.2195x over previous
//
#include <hip/hip_runtime.h>

namespace {

constexpr int    TT     = 2048;
constexpr int    BB     = 128;
constexpr int    CHUNK  = 8;                  // timesteps per chunk (shfl scan width)
constexpr int    NCHUNK = TT / CHUNK;         // 256 chunks per batch
constexpr float  DT     = 0.02f;
constexpr size_t HALF   = (size_t)TT * BB * 16;   // floats per (real|imag) half of d_out

// C = A @ B, complex 4x4, row-major flat [16]
__device__ __forceinline__ void cmm(const float* __restrict__ ar, const float* __restrict__ ai,
                                    const float* __restrict__ br, const float* __restrict__ bi,
                                    float* __restrict__ cr, float* __restrict__ ci) {
#pragma unroll
    for (int i = 0; i < 4; ++i) {
#pragma unroll
        for (int j = 0; j < 4; ++j) {
            float sr = 0.f, si = 0.f;
#pragma unroll
            for (int k = 0; k < 4; ++k) {
                const float xr = ar[i * 4 + k], xi = ai[i * 4 + k];
                const float yr = br[k * 4 + j], yi = bi[k * 4 + j];
                sr = fmaf(xr, yr, sr);
                sr = fmaf(-xi, yi, sr);
                si = fmaf(xr, yi, si);
                si = fmaf(xi, yr, si);
            }
            cr[i * 4 + j] = sr;
            ci[i * 4 + j] = si;
        }
    }
}

// bf16 truncation pack: two f32 -> one uint (lo = a, hi = b)
__device__ __forceinline__ unsigned int pack2(float a, float b) {
    return (__float_as_uint(a) >> 16) | (__float_as_uint(b) & 0xFFFF0000u);
}
__device__ __forceinline__ float unlo(unsigned int u) { return __uint_as_float(u << 16); }
__device__ __forceinline__ float unhi(unsigned int u) { return __uint_as_float(u & 0xFFFF0000u); }

} // namespace

// ---------------------------------------------------------------------------
// kA: expm (deg-4 PS Taylor) + 8-lane Kogge-Stone chunk prefix.
//   gid = b*TT + t, so H read and L write are fully coalesced.
//   L stored bf16-packed: 4 uint4 per matrix (re 2, im 2) at [b][t].
//   Chunk totals (f32, 4 MB) -> totals.
// ---------------------------------------------------------------------------
__global__ __launch_bounds__(256) void kA_expm_scan(const float* __restrict__ hr,
                                                    const float* __restrict__ hi,
                                                    uint4* __restrict__ L,
                                                    float* __restrict__ totals) {
    const int gid  = blockIdx.x * 256 + threadIdx.x;  // b*TT + t
    const int b    = gid >> 11;
    const int t    = gid & (TT - 1);
    const int sub  = t & (CHUNK - 1);
    const int c    = t >> 3;                          // chunk within batch
    const int lane = threadIdx.x & 63;

    // ---- load A = -i*DT*H: a_r = DT*hi, a_i = -DT*hr (coalesced)
    float a_r[16], a_i[16];
    {
        const float4* p4r = reinterpret_cast<const float4*>(hr) + (size_t)gid * 4;
        const float4* p4i = reinterpret_cast<const float4*>(hi) + (size_t)gid * 4;
#pragma unroll
        for (int v = 0; v < 4; ++v) {
            const float4 rr = p4r[v];
            const float4 im = p4i[v];
            a_r[v * 4 + 0] = DT * im.x;  a_i[v * 4 + 0] = -DT * rr.x;
            a_r[v * 4 + 1] = DT * im.y;  a_i[v * 4 + 1] = -DT * rr.y;
            a_r[v * 4 + 2] = DT * im.z;  a_i[v * 4 + 2] = -DT * rr.z;
            a_r[v * 4 + 3] = DT * im.w;  a_i[v * 4 + 3] = -DT * rr.w;
        }
    }

    // ---- expm deg-4 PS: E = I + A + A2 @ (I/2 + A/6 + A2/24)
    float er[16], ei[16];
    {
        float a2r[16], a2i[16];
        cmm(a_r, a_i, a_r, a_i, a2r, a2i);
        float tr[16], ti[16];
#pragma unroll
        for (int e = 0; e < 16; ++e) {
            const float d = (e % 5 == 0) ? 1.0f : 0.0f;
            tr[e] = fmaf(a_r[e], 1.f / 6.f, d * 0.5f);
            tr[e] = fmaf(a2r[e], 1.f / 24.f, tr[e]);
            ti[e] = a_i[e] * (1.f / 6.f);
            ti[e] = fmaf(a2i[e], 1.f / 24.f, ti[e]);
        }
        cmm(a2r, a2i, tr, ti, er, ei);
#pragma unroll
        for (int e = 0; e < 16; ++e) {
            const float d = (e % 5 == 0) ? 1.0f : 0.0f;
            er[e] = er[e] + d + a_r[e];
            ei[e] = ei[e] + a_i[e];
        }
    }

    // ---- Kogge-Stone inclusive prefix over the 8-lane chunk group (3 rounds)
#pragma unroll
    for (int d = 1; d < CHUNK; d <<= 1) {
        int src = lane - d;
        if (src < 0) src = 0;               // clamped junk, discarded by select
        float qr[16], qi[16];
#pragma unroll
        for (int e = 0; e < 16; ++e) {
            qr[e] = __shfl(er[e], src, 64);
            qi[e] = __shfl(ei[e], src, 64);
        }
        float nr[16], ni[16];
        cmm(er, ei, qr, qi, nr, ni);
        const bool pred = (sub >= d);
#pragma unroll
        for (int e = 0; e < 16; ++e) {
            er[e] = pred ? nr[e] : er[e];
            ei[e] = pred ? ni[e] : ei[e];
        }
    }

    // ---- chunk totals (f32)
    if (sub == CHUNK - 1) {
        float* tp = totals + ((size_t)b * NCHUNK + c) * 32;
#pragma unroll
        for (int e = 0; e < 16; ++e) {
            tp[e]      = er[e];
            tp[16 + e] = ei[e];
        }
    }

    // ---- L bf16-packed, coalesced: 4 uint4 per matrix
    {
        uint4 w0, w1, w2, w3;
        w0.x = pack2(er[0],  er[1]);   w0.y = pack2(er[2],  er[3]);
        w0.z = pack2(er[4],  er[5]);   w0.w = pack2(er[6],  er[7]);
        w1.x = pack2(er[8],  er[9]);   w1.y = pack2(er[10], er[11]);
        w1.z = pack2(er[12], er[13]);  w1.w = pack2(er[14], er[15]);
        w2.x = pack2(ei[0],  ei[1]);   w2.y = pack2(ei[2],  ei[3]);
        w2.z = pack2(ei[4],  ei[5]);   w2.w = pack2(ei[6],  ei[7]);
        w3.x = pack2(ei[8],  ei[9]);   w3.y = pack2(ei[10], ei[11]);
        w3.z = pack2(ei[12], ei[13]);  w3.w = pack2(ei[14], ei[15]);
        uint4* Lp = L + (size_t)gid * 4;
        Lp[0] = w0; Lp[1] = w1; Lp[2] = w2; Lp[3] = w3;
    }
}

// ---------------------------------------------------------------------------
// kC: carries. One block per batch (256 threads = 256 chunks).
//   M[0] = state0[b], M[ct] = total[b][ct-1]; 8-round KS in LDS (SoA).
// ---------------------------------------------------------------------------
__global__ __launch_bounds__(256) void kC_carry(const float* __restrict__ totals,
                                                const float* __restrict__ sr,
                                                const float* __restrict__ si,
                                                float* __restrict__ carry) {
    __shared__ float sRe[16][NCHUNK];
    __shared__ float sIm[16][NCHUNK];

    const int ct = threadIdx.x;             // 0..255
    const int b  = blockIdx.x;

    float pr[16], pi[16];
    if (ct == 0) {
#pragma unroll
        for (int e = 0; e < 16; ++e) {
            pr[e] = sr[b * 16 + e];
            pi[e] = si[b * 16 + e];
        }
    } else {
        const float* tp = totals + ((size_t)b * NCHUNK + ct - 1) * 32;
#pragma unroll
        for (int e = 0; e < 16; ++e) {
            pr[e] = tp[e];
            pi[e] = tp[16 + e];
        }
    }

#pragma unroll
    for (int e = 0; e < 16; ++e) {
        sRe[e][ct] = pr[e];
        sIm[e][ct] = pi[e];
    }
    __syncthreads();

#pragma unroll
    for (int d = 1; d < NCHUNK; d <<= 1) {
        if (ct >= d) {
            float qr[16], qi[16];
#pragma unroll
            for (int e = 0; e < 16; ++e) {
                qr[e] = sRe[e][ct - d];
                qi[e] = sIm[e][ct - d];
            }
            float nr[16], ni[16];
            cmm(pr, pi, qr, qi, nr, ni);
#pragma unroll
            for (int e = 0; e < 16; ++e) {
                pr[e] = nr[e];
                pi[e] = ni[e];
            }
        }
        __syncthreads();
        if (ct >= d) {
#pragma unroll
            for (int e = 0; e < 16; ++e) {
                sRe[e][ct] = pr[e];
                sIm[e][ct] = pi[e];
            }
        }
        __syncthreads();
    }

    float* cp = carry + ((size_t)b * NCHUNK + ct) * 32;
#pragma unroll
    for (int e = 0; e < 16; ++e) {
        cp[e]      = pr[e];
        cp[16 + e] = pi[e];
    }
}

// ---------------------------------------------------------------------------
// kD: out[t,b] = L[b,t] @ carry[b][t/8], [b][t] -> [t][b] via LDS transpose.
// Tile: 16 t x 16 b matrices / block. Row pad 17 -> <=2-way aliasing (free).
// ---------------------------------------------------------------------------
__global__ __launch_bounds__(256) void kD_final(const uint4* __restrict__ L,
                                                const float* __restrict__ carry,
                                                float* __restrict__ out) {
    __shared__ float lds[32 * 16 * 17];     // [e 0..31][bloc][tloc(+pad)]

    const int bid   = blockIdx.x;           // 0..1023
    const int tileT = bid & 127;
    const int tileB = bid >> 7;
    const int t0 = tileT * 16, b0 = tileB * 16;
    const int tid = threadIdx.x;

    // ---- phase 1: read L (bf16) coalesced, multiply by carry, stage to LDS
    {
        const int bloc = tid >> 4, tloc = tid & 15;
        const int tt = t0 + tloc;
        const size_t gi = ((size_t)(b0 + bloc) * TT + tt);

        const uint4* Lp = L + gi * 4;
        const uint4 w0 = Lp[0], w1 = Lp[1], w2 = Lp[2], w3 = Lp[3];
        float l_r[16], l_i[16];
        l_r[0]  = unlo(w0.x); l_r[1]  = unhi(w0.x); l_r[2]  = unlo(w0.y); l_r[3]  = unhi(w0.y);
        l_r[4]  = unlo(w0.z); l_r[5]  = unhi(w0.z); l_r[6]  = unlo(w0.w); l_r[7]  = unhi(w0.w);
        l_r[8]  = unlo(w1.x); l_r[9]  = unhi(w1.x); l_r[10] = unlo(w1.y); l_r[11] = unhi(w1.y);
        l_r[12] = unlo(w1.z); l_r[13] = unhi(w1.z); l_r[14] = unlo(w1.w); l_r[15] = unhi(w1.w);
        l_i[0]  = unlo(w2.x); l_i[1]  = unhi(w2.x); l_i[2]  = unlo(w2.y); l_i[3]  = unhi(w2.y);
        l_i[4]  = unlo(w2.z); l_i[5]  = unhi(w2.z); l_i[6]  = unlo(w2.w); l_i[7]  = unhi(w2.w);
        l_i[8]  = unlo(w3.x); l_i[9]  = unhi(w3.x); l_i[10] = unlo(w3.y); l_i[11] = unhi(w3.y);
        l_i[12] = unlo(w3.z); l_i[13] = unhi(w3.z); l_i[14] = unlo(w3.w); l_i[15] = unhi(w3.w);

        float c_r[16], c_i[16];
        const float* cp = carry + ((size_t)(b0 + bloc) * NCHUNK + (tt >> 3)) * 32;
#pragma unroll
        for (int e = 0; e < 16; ++e) {
            c_r[e] = cp[e];
            c_i[e] = cp[16 + e];
        }

        float o_r[16], o_i[16];
        cmm(l_r, l_i, c_r, c_i, o_r, o_i);

        const int slot = bloc * 17 + tloc;
#pragma unroll
        for (int e = 0; e < 16; ++e) {
            lds[e * 272 + slot]        = o_r[e];
            lds[(e + 16) * 272 + slot] = o_i[e];
        }
    }
    __syncthreads();

    // ---- phase 2: read transposed from LDS, write out coalesced in [t][b]
    {
        const int u = tid >> 4;             // t offset in tile
        const int v = tid & 15;             // b offset in tile
        const int slot = v * 17 + u;

        float r2[16], i2[16];
#pragma unroll
        for (int e = 0; e < 16; ++e) {
            r2[e] = lds[e * 272 + slot];
            i2[e] = lds[(e + 16) * 272 + slot];
        }

        const size_t oi = ((size_t)(t0 + u) * BB + (b0 + v)) * 16;
        float4* orp = reinterpret_cast<float4*>(out + oi);
        float4* oip = reinterpret_cast<float4*>(out + HALF + oi);
#pragma unroll
        for (int w = 0; w < 4; ++w) {
            orp[w] = make_float4(r2[w * 4 + 0], r2[w * 4 + 1], r2[w * 4 + 2], r2[w * 4 + 3]);
            oip[w] = make_float4(i2[w * 4 + 0], i2[w * 4 + 1], i2[w * 4 + 2], i2[w * 4 + 3]);
        }
    }
}

extern "C" void kernel_launch(void* const* d_in, const int* in_sizes, int n_in,
                              void* d_out, int out_size, void* d_ws, size_t ws_size,
                              hipStream_t stream) {
    const float* hr = (const float*)d_in[0];
    const float* hi = (const float*)d_in[1];
    const float* sr = (const float*)d_in[2];
    const float* si = (const float*)d_in[3];
    float* out    = (float*)d_out;
    float* totals = (float*)d_ws;                                   // 4 MiB
    float* carry  = (float*)d_ws + (size_t)BB * NCHUNK * 32;        // 4 MiB
    uint4* L      = (uint4*)((float*)d_ws + 2 * (size_t)BB * NCHUNK * 32);  // 16.8 MB

    kA_expm_scan<<<(BB * TT) / 256, 256, 0, stream>>>(hr, hi, L, totals);
    kC_carry    <<<BB, 256, 0, stream>>>(totals, sr, si, carry);
    kD_final    <<<(BB * TT) / 256, 256, 0, stream>>>(L, carry, out);
}